// Round 1
// baseline (217.371 us; speedup 1.0000x reference)
//
#include <hip/hip_runtime.h>
#include <hip/hip_bf16.h>
#include <math.h>

typedef __bf16 bf16;
typedef __attribute__((ext_vector_type(8))) __bf16 bf16x8;
typedef __attribute__((ext_vector_type(4))) float f32x4;

typedef __attribute__((address_space(1))) void* as1ptr;
typedef __attribute__((address_space(3))) void* as3ptr;

__device__ __forceinline__ void gload16(const void* g, void* lds) {
  __builtin_amdgcn_global_load_lds((as1ptr)(unsigned long long)(g),
                                   (as3ptr)(unsigned long long)(lds), 16, 0, 0);
}

#define MFMA16(a, b, c) __builtin_amdgcn_mfma_f32_16x16x32_bf16((a), (b), (c), 0, 0, 0)

#define SEQ 4096
#define EMB 768
#define QSCALE 0.036084391824351615f  // 1/sqrt(768); reference scales by sqrt(embed_dim)

// ---------------- f32 -> bf16 convert (8 elems/thread, vectorized) ----------------
__global__ void cvt_bf16_kernel(const float* __restrict__ in, bf16* __restrict__ out) {
  int i = (blockIdx.x * 256 + threadIdx.x) * 8;
  float4 a = *(const float4*)(in + i);
  float4 b = *(const float4*)(in + i + 4);
  bf16x8 v;
  v[0] = (bf16)a.x; v[1] = (bf16)a.y; v[2] = (bf16)a.z; v[3] = (bf16)a.w;
  v[4] = (bf16)b.x; v[5] = (bf16)b.y; v[6] = (bf16)b.z; v[7] = (bf16)b.w;
  *(bf16x8*)(out + i) = v;
}

// ---------------- GEMM: out[m][n] = sum_k A[m][k]*B[n][k] + bias[n] ----------------
// MODE 0: f32 row-major output (final projection).
// MODE 1: QKV: blockIdx.y in [0,18): mat = y/6 selects {Q,K,V}; Q scaled+head-major,
//         K stored byte-swizzled (byte ^= (s&7)<<4 within 128B row), V head-major.
template <int MODE>
__global__ __launch_bounds__(256)
void gemm_bt_kernel(const bf16* __restrict__ A,
                    const bf16* __restrict__ B0, const bf16* __restrict__ B1,
                    const bf16* __restrict__ B2,
                    const float* __restrict__ bias0, const float* __restrict__ bias1,
                    const float* __restrict__ bias2,
                    float* __restrict__ outF, bf16* __restrict__ Qh,
                    char* __restrict__ Kswz, bf16* __restrict__ Vh) {
  __shared__ __attribute__((aligned(16))) char Asb[8192];
  __shared__ __attribute__((aligned(16))) char Bsb[8192];
  const int tid = threadIdx.x;
  const int wid = tid >> 6, lane = tid & 63;
  const int g = lane >> 4, c16 = lane & 15;
  const int wr = wid >> 1, wc = wid & 1;
  const int bm0 = blockIdx.x * 128;

  const bf16* Bp;
  const float* bias;
  int nb, mat = 0;
  if (MODE == 1) {
    mat = blockIdx.y / 6;
    nb = (blockIdx.y % 6) * 128;
    Bp = (mat == 0) ? B0 : (mat == 1 ? B1 : B2);
    bias = (mat == 0) ? bias0 : (mat == 1 ? bias1 : bias2);
  } else {
    nb = blockIdx.y * 128;
    Bp = B0;
    bias = bias0;
  }

  f32x4 acc[4][4];
#pragma unroll
  for (int i = 0; i < 4; i++)
#pragma unroll
    for (int j = 0; j < 4; j++) acc[i][j] = f32x4{0.f, 0.f, 0.f, 0.f};

  for (int kk = 0; kk < EMB / 32; ++kk) {
    __syncthreads();
#pragma unroll
    for (int c = 0; c < 2; ++c) {
      int ob = c * 4096 + tid * 16;
      int row = ob >> 6, colb = ob & 63;
      gload16((const char*)A + (size_t)(bm0 + row) * (EMB * 2) + kk * 64 + colb,
              Asb + c * 4096 + wid * 1024);
      gload16((const char*)Bp + (size_t)(nb + row) * (EMB * 2) + kk * 64 + colb,
              Bsb + c * 4096 + wid * 1024);
    }
    __syncthreads();
    bf16x8 a[4], b[4];
#pragma unroll
    for (int i = 0; i < 4; i++)
      a[i] = *(const bf16x8*)(Asb + (wr * 64 + i * 16 + c16) * 64 + g * 16);
#pragma unroll
    for (int j = 0; j < 4; j++)
      b[j] = *(const bf16x8*)(Bsb + (wc * 64 + j * 16 + c16) * 64 + g * 16);
#pragma unroll
    for (int i = 0; i < 4; i++)
#pragma unroll
      for (int j = 0; j < 4; j++) acc[i][j] = MFMA16(a[i], b[j], acc[i][j]);
  }

#pragma unroll
  for (int i = 0; i < 4; i++) {
#pragma unroll
    for (int j = 0; j < 4; j++) {
      int colL = nb + wc * 64 + j * 16 + c16;
      float bval = bias[colL];
#pragma unroll
      for (int r = 0; r < 4; r++) {
        int row = bm0 + wr * 64 + i * 16 + 4 * g + r;
        float val = acc[i][j][r] + bval;
        if (MODE == 0) {
          outF[(size_t)row * EMB + colL] = val;
        } else {
          int hh = colL >> 6, d = colL & 63;
          if (mat == 0) {
            Qh[((size_t)hh * SEQ + row) * 64 + d] = (bf16)(val * QSCALE);
          } else if (mat == 1) {
            *(bf16*)(Kswz + ((size_t)hh * SEQ + row) * 128 +
                     ((d * 2) ^ ((row & 7) << 4))) = (bf16)val;
          } else {
            Vh[((size_t)hh * SEQ + row) * 64 + d] = (bf16)val;
          }
        }
      }
    }
  }
}

// ---------------- V transpose: [h][s][64] -> swizzled [h][d][s] ----------------
__global__ __launch_bounds__(256)
void transpose_v_kernel(const bf16* __restrict__ Vh, char* __restrict__ Vswz) {
  __shared__ bf16 t[64][65];
  const int tid = threadIdx.x;
  const int h = blockIdx.y;
  const int s0 = blockIdx.x * 64;
  {
    int row = tid >> 2, seg = (tid & 3) * 16;
    const bf16* src = Vh + ((size_t)h * SEQ + s0 + row) * 64 + seg;
    bf16x8 a = *(const bf16x8*)(src);
    bf16x8 b = *(const bf16x8*)(src + 8);
#pragma unroll
    for (int j = 0; j < 8; j++) {
      t[row][seg + j] = a[j];
      t[row][seg + 8 + j] = b[j];
    }
  }
  __syncthreads();
  {
    int d = tid >> 2, j0 = (tid & 3) * 16;
    bf16x8 o1, o2;
#pragma unroll
    for (int j = 0; j < 8; j++) {
      o1[j] = t[j0 + j][d];
      o2[j] = t[j0 + 8 + j][d];
    }
    size_t rb = ((size_t)h * 64 + d) * 8192 + (size_t)(s0 >> 6) * 128;
    int sw = (d & 7) << 4;
    *(bf16x8*)(Vswz + rb + ((j0 * 2) ^ sw)) = o1;
    *(bf16x8*)(Vswz + rb + ((j0 * 2 + 16) ^ sw)) = o2;
  }
}

// ---------------- Flash attention: 4 waves x 16 q-rows, KVB=64 ----------------
__global__ __launch_bounds__(256)
void attn_kernel(const char* __restrict__ Kswz, const char* __restrict__ Vswz,
                 const bf16* __restrict__ Qh, const unsigned char* __restrict__ mask,
                 bf16* __restrict__ O) {
  __shared__ __attribute__((aligned(16))) char Kt[8192];
  __shared__ __attribute__((aligned(16))) char Vt[8192];
  __shared__ __attribute__((aligned(16))) char Pl[4][2048];
  const int tid = threadIdx.x;
  const int wid = tid >> 6, lane = tid & 63;
  const int g = lane >> 4, c16 = lane & 15;
  const int h = blockIdx.y;
  const int q0 = blockIdx.x * 64 + wid * 16;

  bf16x8 qa0, qa1;
  {
    const bf16* qp = Qh + ((size_t)h * SEQ + q0 + c16) * 64 + g * 8;
    qa0 = *(const bf16x8*)(qp);
    qa1 = *(const bf16x8*)(qp + 32);
  }

  f32x4 o[4];
#pragma unroll
  for (int f = 0; f < 4; ++f) o[f] = f32x4{0.f, 0.f, 0.f, 0.f};
  float m_[4], l_[4];
#pragma unroll
  for (int r = 0; r < 4; r++) {
    m_[r] = -INFINITY;
    l_[r] = 0.f;
  }

  const size_t kbase = (size_t)h * SEQ * 128;
  const size_t vbase = (size_t)h * 64 * 8192;

  for (int t = 0; t < SEQ / 64; ++t) {
    __syncthreads();
#pragma unroll
    for (int c = 0; c < 2; ++c) {
      int ob = c * 4096 + tid * 16;
      int row = ob >> 7, off = ob & 127;
      gload16(Kswz + kbase + (size_t)(t * 64 + row) * 128 + off, Kt + c * 4096 + wid * 1024);
      gload16(Vswz + vbase + (size_t)row * 8192 + (size_t)t * 128 + off, Vt + c * 4096 + wid * 1024);
    }
    __syncthreads();

    // S = Q K^T  (16 q-rows x 64 keys per wave)
    f32x4 sc[4];
#pragma unroll
    for (int cf = 0; cf < 4; ++cf) {
      int kvl = cf * 16 + c16;
      int sw = (kvl & 7) << 4;
      bf16x8 k0 = *(const bf16x8*)(Kt + kvl * 128 + ((g * 16) ^ sw));
      bf16x8 k1 = *(const bf16x8*)(Kt + kvl * 128 + ((64 + g * 16) ^ sw));
      f32x4 z = f32x4{0.f, 0.f, 0.f, 0.f};
      z = MFMA16(qa0, k0, z);
      z = MFMA16(qa1, k1, z);
      sc[cf] = z;
    }
    // padding mask (True = masked out)
#pragma unroll
    for (int cf = 0; cf < 4; ++cf) {
      if (mask[t * 64 + cf * 16 + c16]) {
#pragma unroll
        for (int r = 0; r < 4; r++) sc[cf][r] = -INFINITY;
      }
    }
    // online softmax: row-max across the 16 lanes holding this row's columns
    float mt[4];
#pragma unroll
    for (int r = 0; r < 4; r++)
      mt[r] = fmaxf(fmaxf(sc[0][r], sc[1][r]), fmaxf(sc[2][r], sc[3][r]));
#pragma unroll
    for (int off = 1; off <= 8; off <<= 1)
#pragma unroll
      for (int r = 0; r < 4; r++) mt[r] = fmaxf(mt[r], __shfl_xor(mt[r], off));
    float corr[4];
#pragma unroll
    for (int r = 0; r < 4; r++) {
      float mn = fmaxf(m_[r], mt[r]);
      corr[r] = (m_[r] > -1e37f) ? __expf(m_[r] - mn) : 0.f;
      m_[r] = mn;
    }
    float p[4][4];
#pragma unroll
    for (int cf = 0; cf < 4; ++cf)
#pragma unroll
      for (int r = 0; r < 4; r++) p[cf][r] = __expf(sc[cf][r] - m_[r]);
#pragma unroll
    for (int r = 0; r < 4; r++)
      l_[r] = l_[r] * corr[r] + (p[0][r] + p[1][r]) + (p[2][r] + p[3][r]);
#pragma unroll
    for (int f = 0; f < 4; ++f)
#pragma unroll
      for (int r = 0; r < 4; r++) o[f][r] *= corr[r];

    // P: C-layout -> A-fragment layout via swizzled per-wave LDS buffer
    char* pw = Pl[wid];
#pragma unroll
    for (int cf = 0; cf < 4; ++cf)
#pragma unroll
      for (int r = 0; r < 4; r++) {
        int row = 4 * g + r, col = cf * 16 + c16;
        *(bf16*)(pw + row * 128 + ((col * 2) ^ ((row & 7) << 4))) = (bf16)p[cf][r];
      }
    __asm__ volatile("s_waitcnt lgkmcnt(0)" ::: "memory");
    bf16x8 pa0 = *(const bf16x8*)(pw + c16 * 128 + ((g * 16) ^ ((c16 & 7) << 4)));
    bf16x8 pa1 = *(const bf16x8*)(pw + c16 * 128 + ((64 + g * 16) ^ ((c16 & 7) << 4)));
    // O += P V
#pragma unroll
    for (int f = 0; f < 4; ++f) {
      int dr = f * 16 + c16;
      int sw = (dr & 7) << 4;
      bf16x8 v0 = *(const bf16x8*)(Vt + dr * 128 + ((g * 16) ^ sw));
      bf16x8 v1 = *(const bf16x8*)(Vt + dr * 128 + ((64 + g * 16) ^ sw));
      o[f] = MFMA16(pa0, v0, o[f]);
      o[f] = MFMA16(pa1, v1, o[f]);
    }
  }

#pragma unroll
  for (int off = 1; off <= 8; off <<= 1)
#pragma unroll
    for (int r = 0; r < 4; r++) l_[r] += __shfl_xor(l_[r], off);
#pragma unroll
  for (int f = 0; f < 4; ++f)
#pragma unroll
    for (int r = 0; r < 4; r++) {
      int row = q0 + 4 * g + r;
      int col = h * 64 + f * 16 + c16;
      O[(size_t)row * EMB + col] = (bf16)(o[f][r] / l_[r]);
    }
}

extern "C" void kernel_launch(void* const* d_in, const int* in_sizes, int n_in,
                              void* d_out, int out_size, void* d_ws, size_t ws_size,
                              hipStream_t stream) {
  (void)in_sizes; (void)n_in; (void)out_size; (void)ws_size;
  const float* x = (const float*)d_in[0];
  const unsigned char* mask = (const unsigned char*)d_in[1];
  const float* Wq = (const float*)d_in[2];
  const float* bq = (const float*)d_in[3];
  const float* Wk = (const float*)d_in[4];
  const float* bk = (const float*)d_in[5];
  const float* Wv = (const float*)d_in[6];
  const float* bv = (const float*)d_in[7];
  const float* Wo = (const float*)d_in[8];
  const float* bo = (const float*)d_in[9];
  float* out = (float*)d_out;
  char* ws = (char*)d_ws;

  bf16* xb   = (bf16*)(ws + 0);          // 4096x768 bf16        (6291456 B)
  bf16* Wqb  = (bf16*)(ws + 6291456);    // 768x768 bf16         (1179648 B)
  bf16* Wkb  = (bf16*)(ws + 7471104);
  bf16* Wvb  = (bf16*)(ws + 8650752);
  bf16* Wob  = (bf16*)(ws + 9830400);
  bf16* Qh   = (bf16*)(ws + 11010048);   // [12][4096][64] bf16, pre-scaled
  char* Kswz = ws + 17301504;            // [12][4096] rows of 128B, XOR-swizzled
  bf16* Vh   = (bf16*)(ws + 23592960);   // [12][4096][64] bf16
  char* Vswz = ws + 29884416;            // [12][64] rows of 8192B, XOR-swizzled
  bf16* Obuf = (bf16*)(ws + 36175872);   // [4096][768] bf16

  cvt_bf16_kernel<<<1536, 256, 0, stream>>>(x, xb);
  cvt_bf16_kernel<<<288, 256, 0, stream>>>(Wq, Wqb);
  cvt_bf16_kernel<<<288, 256, 0, stream>>>(Wk, Wkb);
  cvt_bf16_kernel<<<288, 256, 0, stream>>>(Wv, Wvb);
  cvt_bf16_kernel<<<288, 256, 0, stream>>>(Wo, Wob);

  gemm_bt_kernel<1><<<dim3(32, 18), 256, 0, stream>>>(
      xb, Wqb, Wkb, Wvb, bq, bk, bv, nullptr, Qh, Kswz, Vh);
  transpose_v_kernel<<<dim3(64, 12), 256, 0, stream>>>(Vh, Vswz);
  attn_kernel<<<dim3(64, 12), 256, 0, stream>>>(Kswz, Vswz, Qh, mask, Obuf);
  gemm_bt_kernel<0><<<dim3(32, 6), 256, 0, stream>>>(
      Obuf, Wob, nullptr, nullptr, bo, nullptr, nullptr, out, nullptr, nullptr, nullptr);
}

// Round 2
// 147.883 us; speedup vs baseline: 1.4699x; 1.4699x over previous
//
#include <hip/hip_runtime.h>
#include <hip/hip_bf16.h>
#include <math.h>

typedef __bf16 bf16;
typedef __attribute__((ext_vector_type(8))) __bf16 bf16x8;
typedef __attribute__((ext_vector_type(4))) __bf16 bf16x4;
typedef __attribute__((ext_vector_type(4))) float f32x4;

typedef __attribute__((address_space(1))) void* as1ptr;
typedef __attribute__((address_space(3))) void* as3ptr;

__device__ __forceinline__ void gload16(const void* g, void* lds) {
  __builtin_amdgcn_global_load_lds((as1ptr)(unsigned long long)(g),
                                   (as3ptr)(unsigned long long)(lds), 16, 0, 0);
}

#define MFMA16(a, b, c) __builtin_amdgcn_mfma_f32_16x16x32_bf16((a), (b), (c), 0, 0, 0)
#define EXP2(x) __builtin_amdgcn_exp2f(x)

#define SEQ 4096
#define EMB 768
// 1/sqrt(768) * log2(e): attention scores live in the log2 domain
#define QSC (0.036084391824351615f * 1.4426950408889634f)

// ------------- fused f32->bf16 converts (x, Wq, Wk, Wv, Wo) + mask tile flags -------------
#define NCVT 2688  // 1536 (x) + 4*288 (weights)
__global__ __launch_bounds__(256)
void cvt_all_kernel(const float* __restrict__ x, const float* __restrict__ Wq,
                    const float* __restrict__ Wk, const float* __restrict__ Wv,
                    const float* __restrict__ Wo,
                    bf16* __restrict__ xb, bf16* __restrict__ Wqb, bf16* __restrict__ Wkb,
                    bf16* __restrict__ Wvb, bf16* __restrict__ Wob,
                    const unsigned char* __restrict__ mask, unsigned char* __restrict__ tf) {
  int b = blockIdx.x;
  if (b == NCVT) {  // mask tile flags: tf[t] = any(mask[64t .. 64t+63])
    int t = threadIdx.x;
    if (t < 64) {
      unsigned v = 0;
      const unsigned char* mp = mask + t * 64;
      for (int i = 0; i < 64; i++) v |= mp[i];
      tf[t] = (unsigned char)(v ? 1 : 0);
    }
    return;
  }
  const float* in;
  bf16* out;
  int base;
  if (b < 1536) {
    in = x; out = xb; base = b;
  } else {
    int r = b - 1536, seg = r / 288, off = r % 288;
    in  = (seg == 0) ? Wq  : (seg == 1) ? Wk  : (seg == 2) ? Wv  : Wo;
    out = (seg == 0) ? Wqb : (seg == 1) ? Wkb : (seg == 2) ? Wvb : Wob;
    base = off;
  }
  int i = (base * 256 + threadIdx.x) * 8;
  float4 a = *(const float4*)(in + i);
  float4 c = *(const float4*)(in + i + 4);
  bf16x8 v;
  v[0] = (bf16)a.x; v[1] = (bf16)a.y; v[2] = (bf16)a.z; v[3] = (bf16)a.w;
  v[4] = (bf16)c.x; v[5] = (bf16)c.y; v[6] = (bf16)c.z; v[7] = (bf16)c.w;
  *(bf16x8*)(out + i) = v;
}

// ---------------- GEMM: out[m][n] = sum_k A[m][k]*B[n][k] + bias[n] ----------------
// MODE 0: f32 row-major output (final projection).
// MODE 1: QKV. Q: scaled (1/sqrt(E) * log2e), head-major [h][s][64].
//         K: byte-swizzled rows (byte ^= (s&7)<<4 within 128B row) [h][s].
//         V: transposed+column-permuted+swizzled [h][d][s'] for zero-shuffle PV.
template <int MODE>
__global__ __launch_bounds__(256)
void gemm_bt_kernel(const bf16* __restrict__ A,
                    const bf16* __restrict__ B0, const bf16* __restrict__ B1,
                    const bf16* __restrict__ B2,
                    const float* __restrict__ bias0, const float* __restrict__ bias1,
                    const float* __restrict__ bias2,
                    float* __restrict__ outF, bf16* __restrict__ Qh,
                    char* __restrict__ Kswz, char* __restrict__ Vswz) {
  __shared__ __attribute__((aligned(16))) char Asb[8192];
  __shared__ __attribute__((aligned(16))) char Bsb[8192];
  const int tid = threadIdx.x;
  const int wid = tid >> 6, lane = tid & 63;
  const int g = lane >> 4, c16 = lane & 15;
  const int wr = wid >> 1, wc = wid & 1;
  const int bm0 = blockIdx.x * 128;

  const bf16* Bp;
  const float* bias;
  int nb, mat = 0;
  if (MODE == 1) {
    mat = blockIdx.y / 6;
    nb = (blockIdx.y % 6) * 128;
    Bp = (mat == 0) ? B0 : (mat == 1 ? B1 : B2);
    bias = (mat == 0) ? bias0 : (mat == 1 ? bias1 : bias2);
  } else {
    nb = blockIdx.y * 128;
    Bp = B0;
    bias = bias0;
  }

  f32x4 acc[4][4];
#pragma unroll
  for (int i = 0; i < 4; i++)
#pragma unroll
    for (int j = 0; j < 4; j++) acc[i][j] = f32x4{0.f, 0.f, 0.f, 0.f};

  for (int kk = 0; kk < EMB / 32; ++kk) {
    __syncthreads();
#pragma unroll
    for (int c = 0; c < 2; ++c) {
      int ob = c * 4096 + tid * 16;
      int row = ob >> 6, colb = ob & 63;
      gload16((const char*)A + (size_t)(bm0 + row) * (EMB * 2) + kk * 64 + colb,
              Asb + c * 4096 + wid * 1024);
      gload16((const char*)Bp + (size_t)(nb + row) * (EMB * 2) + kk * 64 + colb,
              Bsb + c * 4096 + wid * 1024);
    }
    __syncthreads();
    bf16x8 a[4], b[4];
#pragma unroll
    for (int i = 0; i < 4; i++)
      a[i] = *(const bf16x8*)(Asb + (wr * 64 + i * 16 + c16) * 64 + g * 16);
#pragma unroll
    for (int j = 0; j < 4; j++)
      b[j] = *(const bf16x8*)(Bsb + (wc * 64 + j * 16 + c16) * 64 + g * 16);
#pragma unroll
    for (int i = 0; i < 4; i++)
#pragma unroll
      for (int j = 0; j < 4; j++) acc[i][j] = MFMA16(a[i], b[j], acc[i][j]);
  }

#pragma unroll
  for (int i = 0; i < 4; i++) {
#pragma unroll
    for (int j = 0; j < 4; j++) {
      int colL = nb + wc * 64 + j * 16 + c16;
      float bval = bias[colL];
#pragma unroll
      for (int r = 0; r < 4; r++) {
        int row = bm0 + wr * 64 + i * 16 + 4 * g + r;
        float val = acc[i][j][r] + bval;
        if (MODE == 0) {
          outF[(size_t)row * EMB + colL] = val;
        } else {
          int hh = colL >> 6, d = colL & 63;
          if (mat == 0) {
            Qh[((size_t)hh * SEQ + row) * 64 + d] = (bf16)(val * QSC);
          } else if (mat == 1) {
            *(bf16*)(Kswz + ((size_t)hh * SEQ + row) * 128 +
                     ((d * 2) ^ ((row & 7) << 4))) = (bf16)val;
          } else {
            // V^T with per-32 column permutation: key k -> slot 8*((k&15)>>2)+4*((k>>4)&1)+(k&3)
            int u5 = 8 * ((row & 15) >> 2) + 4 * ((row >> 4) & 1) + (row & 3);
            int cc = (row & 32) | u5;  // column within the 64-col (128B) tile chunk
            *(bf16*)(Vswz + ((size_t)hh * 64 + d) * 8192 + (size_t)(row >> 6) * 128 +
                     ((cc * 2) ^ ((d & 7) << 4))) = (bf16)val;
          }
        }
      }
    }
  }
}

// -------- Flash attention: swapped QK^T, scalar per-lane softmax, zero-shuffle PV --------
// 4 waves x 16 q-rows, KVB=64, double-buffered K/V staging (2-phase).
__global__ __launch_bounds__(256)
void attn_kernel(const char* __restrict__ Kswz, const char* __restrict__ Vswz,
                 const bf16* __restrict__ Qh, const unsigned char* __restrict__ mask,
                 const unsigned char* __restrict__ tf, bf16* __restrict__ O) {
  __shared__ __attribute__((aligned(16))) char Kt[2][8192];
  __shared__ __attribute__((aligned(16))) char Vt[2][8192];
  const int tid = threadIdx.x;
  const int wid = tid >> 6, lane = tid & 63;
  const int g = (lane >> 4) & 3, c16 = lane & 15;
  const int h = blockIdx.y;
  const int q0 = blockIdx.x * 64 + wid * 16;

  bf16x8 qa0, qa1;  // Q[q=c16][d=8g+j], d-halves
  {
    const bf16* qp = Qh + ((size_t)h * SEQ + q0 + c16) * 64 + g * 8;
    qa0 = *(const bf16x8*)(qp);
    qa1 = *(const bf16x8*)(qp + 32);
  }

  f32x4 ot[4];  // O^T accum: ot[f][r] = O^T[d=f*16+4g+r][q=c16]
#pragma unroll
  for (int f = 0; f < 4; ++f) ot[f] = f32x4{0.f, 0.f, 0.f, 0.f};
  float m_ = -1e38f, l_ = 0.f;

  // staging source pointers (per-thread)
  const char* ksrc = Kswz + (size_t)h * SEQ * 128 + tid * 16;
  const char* vsrc0 = Vswz + ((size_t)h * 64 + (tid >> 3)) * 8192 + (tid & 7) * 16;
  const char* vsrc1 = Vswz + ((size_t)h * 64 + 32 + (tid >> 3)) * 8192 + (tid & 7) * 16;

#define STAGE(t, b)                                                    \
  do {                                                                 \
    gload16(ksrc + (size_t)(t)*8192,        &Kt[b][wid * 1024]);       \
    gload16(ksrc + (size_t)(t)*8192 + 4096, &Kt[b][4096 + wid * 1024]);\
    gload16(vsrc0 + (size_t)(t)*128, &Vt[b][wid * 1024]);              \
    gload16(vsrc1 + (size_t)(t)*128, &Vt[b][4096 + wid * 1024]);       \
  } while (0)

  STAGE(0, 0);
  __syncthreads();

  for (int t = 0; t < SEQ / 64; ++t) {
    const int b = t & 1;
    if (t < SEQ / 64 - 1) STAGE(t + 1, b ^ 1);
    const char* Kb = Kt[b];
    const char* Vb = Vt[b];

    // S^T = mfma(K, Q): lane holds S^T[key=16cf+4g+r][q=c16]
    f32x4 sc[4];
#pragma unroll
    for (int cf = 0; cf < 4; ++cf) {
      int row = cf * 16 + c16, sw = (row & 7) << 4;
      bf16x8 k0 = *(const bf16x8*)(Kb + row * 128 + ((g * 16) ^ sw));
      bf16x8 k1 = *(const bf16x8*)(Kb + row * 128 + ((64 + g * 16) ^ sw));
      f32x4 z = f32x4{0.f, 0.f, 0.f, 0.f};
      z = MFMA16(k0, qa0, z);
      z = MFMA16(k1, qa1, z);
      sc[cf] = z;
    }

    if (tf[t]) {  // rare path: padding mask present in this tile
#pragma unroll
      for (int cf = 0; cf < 4; ++cf)
#pragma unroll
        for (int r = 0; r < 4; r++)
          if (mask[t * 64 + cf * 16 + 4 * g + r]) sc[cf][r] = -INFINITY;
    }

    // per-lane row max (single q per lane) + reduce across the 4 g-lanes
    float x0 = fmaxf(fmaxf(sc[0][0], sc[0][1]), fmaxf(sc[0][2], sc[0][3]));
    float x1 = fmaxf(fmaxf(sc[1][0], sc[1][1]), fmaxf(sc[1][2], sc[1][3]));
    float x2 = fmaxf(fmaxf(sc[2][0], sc[2][1]), fmaxf(sc[2][2], sc[2][3]));
    float x3 = fmaxf(fmaxf(sc[3][0], sc[3][1]), fmaxf(sc[3][2], sc[3][3]));
    float mt = fmaxf(fmaxf(x0, x1), fmaxf(x2, x3));
    mt = fmaxf(mt, __shfl_xor(mt, 16));
    mt = fmaxf(mt, __shfl_xor(mt, 32));

    // defer-max (THR=8 in log2 units)
    if (__any(mt > m_ + 8.f)) {
      float mn = fmaxf(m_, mt);
      float corr = EXP2(m_ - mn);
      l_ *= corr;
#pragma unroll
      for (int f = 0; f < 4; ++f) ot[f] *= corr;
      m_ = mn;
    }

    // p = exp2(s - m); pack in register order = PV B-fragment order (V is key-permuted)
    float p[16];
#pragma unroll
    for (int cf = 0; cf < 4; ++cf)
#pragma unroll
      for (int r = 0; r < 4; r++) p[cf * 4 + r] = EXP2(sc[cf][r] - m_);
    l_ += ((p[0] + p[1]) + (p[2] + p[3])) + ((p[4] + p[5]) + (p[6] + p[7])) +
          (((p[8] + p[9]) + (p[10] + p[11])) + ((p[12] + p[13]) + (p[14] + p[15])));
    bf16x8 pb0, pb1;
#pragma unroll
    for (int e = 0; e < 8; ++e) {
      pb0[e] = (bf16)p[e];
      pb1[e] = (bf16)p[8 + e];
    }

    // O^T += mfma(V^T, P^T): zero cross-lane traffic
#pragma unroll
    for (int f = 0; f < 4; ++f) {
      int row = f * 16 + c16, sw = (row & 7) << 4;
      bf16x8 v0 = *(const bf16x8*)(Vb + row * 128 + ((g * 16) ^ sw));
      bf16x8 v1 = *(const bf16x8*)(Vb + row * 128 + ((64 + g * 16) ^ sw));
      ot[f] = MFMA16(v0, pb0, ot[f]);
      ot[f] = MFMA16(v1, pb1, ot[f]);
    }
    __syncthreads();
  }
#undef STAGE

  l_ += __shfl_xor(l_, 16);
  l_ += __shfl_xor(l_, 32);
  float inv = 1.f / l_;
#pragma unroll
  for (int f = 0; f < 4; ++f) {
    bf16x4 w;
#pragma unroll
    for (int r = 0; r < 4; r++) w[r] = (bf16)(ot[f][r] * inv);
    *(bf16x4*)(O + (size_t)(q0 + c16) * EMB + h * 64 + f * 16 + 4 * g) = w;
  }
}

extern "C" void kernel_launch(void* const* d_in, const int* in_sizes, int n_in,
                              void* d_out, int out_size, void* d_ws, size_t ws_size,
                              hipStream_t stream) {
  (void)in_sizes; (void)n_in; (void)out_size; (void)ws_size;
  const float* x = (const float*)d_in[0];
  const unsigned char* mask = (const unsigned char*)d_in[1];
  const float* Wq = (const float*)d_in[2];
  const float* bq = (const float*)d_in[3];
  const float* Wk = (const float*)d_in[4];
  const float* bk = (const float*)d_in[5];
  const float* Wv = (const float*)d_in[6];
  const float* bv = (const float*)d_in[7];
  const float* Wo = (const float*)d_in[8];
  const float* bo = (const float*)d_in[9];
  float* out = (float*)d_out;
  char* ws = (char*)d_ws;

  bf16* xb   = (bf16*)(ws + 0);          // 4096x768 bf16
  bf16* Wqb  = (bf16*)(ws + 6291456);
  bf16* Wkb  = (bf16*)(ws + 7471104);
  bf16* Wvb  = (bf16*)(ws + 8650752);
  bf16* Wob  = (bf16*)(ws + 9830400);
  bf16* Qh   = (bf16*)(ws + 11010048);   // [12][4096][64] bf16, scaled by QSC
  char* Kswz = ws + 17301504;            // [12][4096] rows of 128B, XOR-swizzled
  char* Vswz = ws + 23592960;            // [12][64] rows of 8192B, perm+swizzled V^T
  bf16* Obuf = (bf16*)(ws + 29884416);   // [4096][768] bf16
  unsigned char* tf = (unsigned char*)(ws + 36175872);  // 64 tile-mask flags

  cvt_all_kernel<<<NCVT + 1, 256, 0, stream>>>(x, Wq, Wk, Wv, Wo, xb, Wqb, Wkb, Wvb,
                                               Wob, mask, tf);
  gemm_bt_kernel<1><<<dim3(32, 18), 256, 0, stream>>>(
      xb, Wqb, Wkb, Wvb, bq, bk, bv, nullptr, Qh, Kswz, Vswz);
  attn_kernel<<<dim3(64, 12), 256, 0, stream>>>(Kswz, Vswz, Qh, mask, tf, Obuf);
  gemm_bt_kernel<0><<<dim3(32, 6), 256, 0, stream>>>(
      Obuf, Wob, nullptr, nullptr, bo, nullptr, nullptr, out, nullptr, nullptr, nullptr);
}

// Round 3
// 144.230 us; speedup vs baseline: 1.5071x; 1.0253x over previous
//
#include <hip/hip_runtime.h>
#include <hip/hip_bf16.h>
#include <math.h>

typedef __bf16 bf16;
typedef __attribute__((ext_vector_type(8))) __bf16 bf16x8;
typedef __attribute__((ext_vector_type(4))) __bf16 bf16x4;
typedef __attribute__((ext_vector_type(4))) float f32x4;

typedef __attribute__((address_space(1))) void* as1ptr;
typedef __attribute__((address_space(3))) void* as3ptr;

__device__ __forceinline__ void gload16(const void* g, void* lds) {
  __builtin_amdgcn_global_load_lds((as1ptr)(unsigned long long)(g),
                                   (as3ptr)(unsigned long long)(lds), 16, 0, 0);
}

#define MFMA16(a, b, c) __builtin_amdgcn_mfma_f32_16x16x32_bf16((a), (b), (c), 0, 0, 0)
#define EXP2(x) __builtin_amdgcn_exp2f(x)
#define WAITV4 asm volatile("s_waitcnt vmcnt(4)" ::: "memory")
#define WAITV0 asm volatile("s_waitcnt vmcnt(0)" ::: "memory")
#define BAR() __builtin_amdgcn_s_barrier()
#define PRIO1() __builtin_amdgcn_s_setprio(1)
#define PRIO0() __builtin_amdgcn_s_setprio(0)

#define SEQ 4096
#define EMB 768
// 1/sqrt(768) * log2(e): attention scores live in the log2 domain
#define QSC (0.036084391824351615f * 1.4426950408889634f)

// ------------- fused f32->bf16 converts (x, Wq, Wk, Wv, Wo) + mask tile-flag bits -------------
#define NCVT 2688  // 1536 (x) + 4*288 (weights)
__global__ __launch_bounds__(256)
void cvt_all_kernel(const float* __restrict__ x, const float* __restrict__ Wq,
                    const float* __restrict__ Wk, const float* __restrict__ Wv,
                    const float* __restrict__ Wo,
                    bf16* __restrict__ xb, bf16* __restrict__ Wqb, bf16* __restrict__ Wkb,
                    bf16* __restrict__ Wvb, bf16* __restrict__ Wob,
                    const unsigned char* __restrict__ mask,
                    unsigned long long* __restrict__ tf64) {
  int b = blockIdx.x;
  if (b == NCVT) {  // bit t of *tf64 = any(mask[64t .. 64t+63]), t = 0..63
    int t = threadIdx.x;
    if (t < 64) {
      unsigned v = 0;
      const unsigned char* mp = mask + t * 64;
      for (int i = 0; i < 64; i++) v |= mp[i];
      unsigned long long bits = __ballot(v != 0);
      if (t == 0) *tf64 = bits;
    }
    return;
  }
  const float* in;
  bf16* out;
  int base;
  if (b < 1536) {
    in = x; out = xb; base = b;
  } else {
    int r = b - 1536, seg = r / 288, off = r % 288;
    in  = (seg == 0) ? Wq  : (seg == 1) ? Wk  : (seg == 2) ? Wv  : Wo;
    out = (seg == 0) ? Wqb : (seg == 1) ? Wkb : (seg == 2) ? Wvb : Wob;
    base = off;
  }
  int i = (base * 256 + threadIdx.x) * 8;
  float4 a = *(const float4*)(in + i);
  float4 c = *(const float4*)(in + i + 4);
  bf16x8 v;
  v[0] = (bf16)a.x; v[1] = (bf16)a.y; v[2] = (bf16)a.z; v[3] = (bf16)a.w;
  v[4] = (bf16)c.x; v[5] = (bf16)c.y; v[6] = (bf16)c.z; v[7] = (bf16)c.w;
  *(bf16x8*)(out + i) = v;
}

// ---------------- GEMM: out[m][n] = sum_k A[m][k]*B[n][k] + bias[n] ----------------
// 3-deep LDS pipeline, counted vmcnt(4), single raw barrier per K-step.
// MODE 0: f32 row-major output (final projection).
// MODE 1: QKV. Q: scaled (1/sqrt(E)*log2e) head-major; K: byte-swizzled rows;
//         V: transposed+column-permuted+swizzled V^T for zero-shuffle PV.
template <int MODE>
__global__ __launch_bounds__(256)
void gemm_bt_kernel(const bf16* __restrict__ A,
                    const bf16* __restrict__ B0, const bf16* __restrict__ B1,
                    const bf16* __restrict__ B2,
                    const float* __restrict__ bias0, const float* __restrict__ bias1,
                    const float* __restrict__ bias2,
                    float* __restrict__ outF, bf16* __restrict__ Qh,
                    char* __restrict__ Kswz, char* __restrict__ Vswz) {
  __shared__ __attribute__((aligned(16))) char Asb[3][8192];
  __shared__ __attribute__((aligned(16))) char Bsb[3][8192];
  const int tid = threadIdx.x;
  const int wid = tid >> 6, lane = tid & 63;
  const int g = lane >> 4, c16 = lane & 15;
  const int wr = wid >> 1, wc = wid & 1;
  const int bm0 = blockIdx.x * 128;

  const bf16* Bp;
  const float* bias;
  int nb, mat = 0;
  if (MODE == 1) {
    mat = blockIdx.y / 6;
    nb = (blockIdx.y % 6) * 128;
    Bp = (mat == 0) ? B0 : (mat == 1 ? B1 : B2);
    bias = (mat == 0) ? bias0 : (mat == 1 ? bias1 : bias2);
  } else {
    nb = blockIdx.y * 128;
    Bp = B0;
    bias = bias0;
  }

  const int arow = tid >> 2, acol = (tid & 3) * 16;  // tid*16 -> (row, 16B-col) in 128x32 tile

#define STAGE_G(k, b)                                                              \
  do {                                                                             \
    gload16((const char*)A + (size_t)(bm0 + arow) * (EMB * 2) + (k)*64 + acol,     \
            &Asb[b][wid * 1024]);                                                  \
    gload16((const char*)A + (size_t)(bm0 + 64 + arow) * (EMB * 2) + (k)*64 + acol,\
            &Asb[b][4096 + wid * 1024]);                                           \
    gload16((const char*)Bp + (size_t)(nb + arow) * (EMB * 2) + (k)*64 + acol,     \
            &Bsb[b][wid * 1024]);                                                  \
    gload16((const char*)Bp + (size_t)(nb + 64 + arow) * (EMB * 2) + (k)*64 + acol,\
            &Bsb[b][4096 + wid * 1024]);                                           \
  } while (0)

  f32x4 acc[4][4];
#pragma unroll
  for (int i = 0; i < 4; i++)
#pragma unroll
    for (int j = 0; j < 4; j++) acc[i][j] = f32x4{0.f, 0.f, 0.f, 0.f};

#define COMPUTE_G(cur)                                                         \
  do {                                                                         \
    bf16x8 a[4], b[4];                                                         \
    _Pragma("unroll") for (int i = 0; i < 4; i++)                              \
        a[i] = *(const bf16x8*)(&Asb[cur][(wr * 64 + i * 16 + c16) * 64 + g * 16]); \
    _Pragma("unroll") for (int j = 0; j < 4; j++)                              \
        b[j] = *(const bf16x8*)(&Bsb[cur][(wc * 64 + j * 16 + c16) * 64 + g * 16]); \
    PRIO1();                                                                   \
    _Pragma("unroll") for (int i = 0; i < 4; i++)                              \
        _Pragma("unroll") for (int j = 0; j < 4; j++)                          \
            acc[i][j] = MFMA16(a[i], b[j], acc[i][j]);                         \
    PRIO0();                                                                   \
  } while (0)

  STAGE_G(0, 0);
  STAGE_G(1, 1);
  int cur = 0;
  for (int kk = 0; kk < EMB / 32 - 1; ++kk) {
    WAITV4;
    BAR();
    if (kk < EMB / 32 - 2) {
      int stb = (cur == 0) ? 2 : cur - 1;  // (kk+2)%3
      STAGE_G(kk + 2, stb);
    }
    COMPUTE_G(cur);
    cur = (cur == 2) ? 0 : cur + 1;
  }
  WAITV0;
  BAR();
  COMPUTE_G(cur);
#undef STAGE_G
#undef COMPUTE_G

#pragma unroll
  for (int i = 0; i < 4; i++) {
#pragma unroll
    for (int j = 0; j < 4; j++) {
      int colL = nb + wc * 64 + j * 16 + c16;
      float bval = bias[colL];
#pragma unroll
      for (int r = 0; r < 4; r++) {
        int row = bm0 + wr * 64 + i * 16 + 4 * g + r;
        float val = acc[i][j][r] + bval;
        if (MODE == 0) {
          outF[(size_t)row * EMB + colL] = val;
        } else {
          int hh = colL >> 6, d = colL & 63;
          if (mat == 0) {
            Qh[((size_t)hh * SEQ + row) * 64 + d] = (bf16)(val * QSC);
          } else if (mat == 1) {
            *(bf16*)(Kswz + ((size_t)hh * SEQ + row) * 128 +
                     ((d * 2) ^ ((row & 7) << 4))) = (bf16)val;
          } else {
            // V^T with per-32 column permutation: key k -> slot 8*((k&15)>>2)+4*((k>>4)&1)+(k&3)
            int u5 = 8 * ((row & 15) >> 2) + 4 * ((row >> 4) & 1) + (row & 3);
            int cc = (row & 32) | u5;
            *(bf16*)(Vswz + ((size_t)hh * 64 + d) * 8192 + (size_t)(row >> 6) * 128 +
                     ((cc * 2) ^ ((d & 7) << 4))) = (bf16)val;
          }
        }
      }
    }
  }
}

// -------- Flash attention: swapped QK^T, zero-shuffle PV, 3-deep counted-vmcnt pipeline --------
__global__ __launch_bounds__(256)
void attn_kernel(const char* __restrict__ Kswz, const char* __restrict__ Vswz,
                 const bf16* __restrict__ Qh, const unsigned char* __restrict__ mask,
                 const unsigned long long* __restrict__ tf64, bf16* __restrict__ O) {
  __shared__ __attribute__((aligned(16))) char Kt[3][8192];
  __shared__ __attribute__((aligned(16))) char Vt[3][8192];
  const int tid = threadIdx.x;
  const int wid = tid >> 6, lane = tid & 63;
  const int g = (lane >> 4) & 3, c16 = lane & 15;
  const int h = blockIdx.y;
  const int q0 = blockIdx.x * 64 + wid * 16;
  const unsigned long long tfb = *tf64;

  bf16x8 qa0, qa1;  // Q[q=c16][d=8g+j], d-halves
  {
    const bf16* qp = Qh + ((size_t)h * SEQ + q0 + c16) * 64 + g * 8;
    qa0 = *(const bf16x8*)(qp);
    qa1 = *(const bf16x8*)(qp + 32);
  }

  f32x4 ot[4];  // O^T accum: ot[f][r] = O^T[d=f*16+4g+r][q=c16]
#pragma unroll
  for (int f = 0; f < 4; ++f) ot[f] = f32x4{0.f, 0.f, 0.f, 0.f};
  float m_ = -1e38f, l_ = 0.f;

  const char* ksrc = Kswz + (size_t)h * SEQ * 128 + tid * 16;
  const char* vsrc0 = Vswz + ((size_t)h * 64 + (tid >> 3)) * 8192 + (tid & 7) * 16;
  const char* vsrc1 = Vswz + ((size_t)h * 64 + 32 + (tid >> 3)) * 8192 + (tid & 7) * 16;

#define STAGE(t, b)                                                    \
  do {                                                                 \
    gload16(ksrc + (size_t)(t)*8192,        &Kt[b][wid * 1024]);       \
    gload16(ksrc + (size_t)(t)*8192 + 4096, &Kt[b][4096 + wid * 1024]);\
    gload16(vsrc0 + (size_t)(t)*128, &Vt[b][wid * 1024]);              \
    gload16(vsrc1 + (size_t)(t)*128, &Vt[b][4096 + wid * 1024]);       \
  } while (0)

#define COMPUTE(t, cur)                                                         \
  do {                                                                          \
    const char* Kb = Kt[cur];                                                   \
    const char* Vb = Vt[cur];                                                   \
    f32x4 sc[4];                                                                \
    bf16x8 k0[4], k1[4];                                                        \
    _Pragma("unroll") for (int cf = 0; cf < 4; ++cf) {                          \
      int row = cf * 16 + c16, sw = (row & 7) << 4;                             \
      k0[cf] = *(const bf16x8*)(Kb + row * 128 + ((g * 16) ^ sw));              \
      k1[cf] = *(const bf16x8*)(Kb + row * 128 + ((64 + g * 16) ^ sw));         \
    }                                                                           \
    PRIO1();                                                                    \
    _Pragma("unroll") for (int cf = 0; cf < 4; ++cf) {                          \
      f32x4 z = f32x4{0.f, 0.f, 0.f, 0.f};                                      \
      z = MFMA16(k0[cf], qa0, z);                                               \
      z = MFMA16(k1[cf], qa1, z);                                               \
      sc[cf] = z;                                                               \
    }                                                                           \
    PRIO0();                                                                    \
    if (tfb & (1ull << (t))) {                                                  \
      _Pragma("unroll") for (int cf = 0; cf < 4; ++cf)                          \
          _Pragma("unroll") for (int r = 0; r < 4; r++)                         \
              if (mask[(t)*64 + cf * 16 + 4 * g + r]) sc[cf][r] = -INFINITY;    \
    }                                                                           \
    float x0 = fmaxf(fmaxf(sc[0][0], sc[0][1]), fmaxf(sc[0][2], sc[0][3]));     \
    float x1 = fmaxf(fmaxf(sc[1][0], sc[1][1]), fmaxf(sc[1][2], sc[1][3]));     \
    float x2 = fmaxf(fmaxf(sc[2][0], sc[2][1]), fmaxf(sc[2][2], sc[2][3]));     \
    float x3 = fmaxf(fmaxf(sc[3][0], sc[3][1]), fmaxf(sc[3][2], sc[3][3]));     \
    float mt = fmaxf(fmaxf(x0, x1), fmaxf(x2, x3));                             \
    mt = fmaxf(mt, __shfl_xor(mt, 16));                                         \
    mt = fmaxf(mt, __shfl_xor(mt, 32));                                         \
    if (__any(mt > m_ + 8.f)) {                                                 \
      float mn = fmaxf(m_, mt);                                                 \
      float corr = EXP2(m_ - mn);                                               \
      l_ *= corr;                                                               \
      _Pragma("unroll") for (int f = 0; f < 4; ++f) ot[f] *= corr;              \
      m_ = mn;                                                                  \
    }                                                                           \
    float p[16];                                                                \
    _Pragma("unroll") for (int cf = 0; cf < 4; ++cf)                            \
        _Pragma("unroll") for (int r = 0; r < 4; r++)                           \
            p[cf * 4 + r] = EXP2(sc[cf][r] - m_);                               \
    l_ += ((p[0] + p[1]) + (p[2] + p[3])) + ((p[4] + p[5]) + (p[6] + p[7])) +   \
          (((p[8] + p[9]) + (p[10] + p[11])) + ((p[12] + p[13]) + (p[14] + p[15]))); \
    bf16x8 pb0, pb1;                                                            \
    _Pragma("unroll") for (int e = 0; e < 8; ++e) {                             \
      pb0[e] = (bf16)p[e];                                                      \
      pb1[e] = (bf16)p[8 + e];                                                  \
    }                                                                           \
    bf16x8 v0[4], v1[4];                                                        \
    _Pragma("unroll") for (int f = 0; f < 4; ++f) {                             \
      int row = f * 16 + c16, sw = (row & 7) << 4;                              \
      v0[f] = *(const bf16x8*)(Vb + row * 128 + ((g * 16) ^ sw));               \
      v1[f] = *(const bf16x8*)(Vb + row * 128 + ((64 + g * 16) ^ sw));          \
    }                                                                           \
    PRIO1();                                                                    \
    _Pragma("unroll") for (int f = 0; f < 4; ++f) {                             \
      ot[f] = MFMA16(v0[f], pb0, ot[f]);                                        \
      ot[f] = MFMA16(v1[f], pb1, ot[f]);                                        \
    }                                                                           \
    PRIO0();                                                                    \
  } while (0)

  STAGE(0, 0);
  STAGE(1, 1);
  int cur = 0;
  for (int t = 0; t < SEQ / 64 - 1; ++t) {
    WAITV4;
    BAR();
    if (t < SEQ / 64 - 2) {
      int stb = (cur == 0) ? 2 : cur - 1;  // (t+2)%3
      STAGE(t + 2, stb);
    }
    COMPUTE(t, cur);
    cur = (cur == 2) ? 0 : cur + 1;
  }
  WAITV0;
  BAR();
  COMPUTE(SEQ / 64 - 1, cur);
#undef STAGE
#undef COMPUTE

  l_ += __shfl_xor(l_, 16);
  l_ += __shfl_xor(l_, 32);
  float inv = 1.f / l_;
#pragma unroll
  for (int f = 0; f < 4; ++f) {
    bf16x4 w;
#pragma unroll
    for (int r = 0; r < 4; r++) w[r] = (bf16)(ot[f][r] * inv);
    *(bf16x4*)(O + (size_t)(q0 + c16) * EMB + h * 64 + f * 16 + 4 * g) = w;
  }
}

extern "C" void kernel_launch(void* const* d_in, const int* in_sizes, int n_in,
                              void* d_out, int out_size, void* d_ws, size_t ws_size,
                              hipStream_t stream) {
  (void)in_sizes; (void)n_in; (void)out_size; (void)ws_size;
  const float* x = (const float*)d_in[0];
  const unsigned char* mask = (const unsigned char*)d_in[1];
  const float* Wq = (const float*)d_in[2];
  const float* bq = (const float*)d_in[3];
  const float* Wk = (const float*)d_in[4];
  const float* bk = (const float*)d_in[5];
  const float* Wv = (const float*)d_in[6];
  const float* bv = (const float*)d_in[7];
  const float* Wo = (const float*)d_in[8];
  const float* bo = (const float*)d_in[9];
  float* out = (float*)d_out;
  char* ws = (char*)d_ws;

  bf16* xb   = (bf16*)(ws + 0);          // 4096x768 bf16
  bf16* Wqb  = (bf16*)(ws + 6291456);
  bf16* Wkb  = (bf16*)(ws + 7471104);
  bf16* Wvb  = (bf16*)(ws + 8650752);
  bf16* Wob  = (bf16*)(ws + 9830400);
  bf16* Qh   = (bf16*)(ws + 11010048);   // [12][4096][64] bf16, scaled by QSC
  char* Kswz = ws + 17301504;            // [12][4096] rows of 128B, XOR-swizzled
  char* Vswz = ws + 23592960;            // [12][64] rows of 8192B, perm+swizzled V^T
  bf16* Obuf = (bf16*)(ws + 29884416);   // [4096][768] bf16
  unsigned long long* tf64 = (unsigned long long*)(ws + 36175872);

  cvt_all_kernel<<<NCVT + 1, 256, 0, stream>>>(x, Wq, Wk, Wv, Wo, xb, Wqb, Wkb, Wvb,
                                               Wob, mask, tf64);
  gemm_bt_kernel<1><<<dim3(32, 18), 256, 0, stream>>>(
      xb, Wqb, Wkb, Wvb, bq, bk, bv, nullptr, Qh, Kswz, Vswz);
  attn_kernel<<<dim3(64, 12), 256, 0, stream>>>(Kswz, Vswz, Qh, mask, tf64, Obuf);
  gemm_bt_kernel<0><<<dim3(32, 6), 256, 0, stream>>>(
      Obuf, Wob, nullptr, nullptr, bo, nullptr, nullptr, out, nullptr, nullptr, nullptr);
}